// Round 3
// baseline (1133.074 us; speedup 1.0000x reference)
//
#include <hip/hip_runtime.h>

typedef unsigned short u16;
typedef __attribute__((ext_vector_type(8))) short bf16x8;
typedef __attribute__((ext_vector_type(4))) float f32x4;

#define GK 4096
#define GN 4096
#define BDIM 4096
#define BROWS 8192
#define BUF 16384

__device__ __forceinline__ u16 f2b(float f) {
    union { float f; unsigned u; } c; c.f = f;
    unsigned u = c.u;
    return (u16)((u + 0x7FFFu + ((u >> 16) & 1u)) >> 16);
}
__device__ __forceinline__ float b2f(u16 h) {
    union { unsigned u; float f; } c; c.u = ((unsigned)h) << 16;
    return c.f;
}
__device__ __forceinline__ void gload16(const void* g, void* l) {
    __builtin_amdgcn_global_load_lds((const __attribute__((address_space(1))) void*)g,
                                     (__attribute__((address_space(3))) void*)l, 16, 0, 0);
}
__device__ __forceinline__ int rfl(int x) { return __builtin_amdgcn_readfirstlane(x); }

template <int N> __device__ __forceinline__ void vwait() {
    if constexpr (N == 0) asm volatile("s_waitcnt vmcnt(0)" ::: "memory");
    if constexpr (N == 2) asm volatile("s_waitcnt vmcnt(2)" ::: "memory");
    if constexpr (N == 6) asm volatile("s_waitcnt vmcnt(6)" ::: "memory");
}

// ==== fused prologue: x->bf16 + colsum  AND  Wgate/Wtemp -> bf16 ====
__global__ void k_prep(const float* __restrict__ x, u16* __restrict__ xb,
                       float* __restrict__ colsum,
                       const float4* __restrict__ wg, ushort4* __restrict__ wgo,
                       const float4* __restrict__ wt, ushort4* __restrict__ wto) {
    __shared__ float red[256][4];
    const int tid = threadIdx.x;
    const int bid = blockIdx.x;
    if (bid < 1024) {
        const int bx = bid & 15, by = bid >> 4;
        const int c4   = bx * 64 + (tid & 63);
        const int rowg = tid >> 6;
        const int r0   = by * 128;
        const float4* x4 = (const float4*)x;
        float sx = 0.f, sy = 0.f, sz = 0.f, sw = 0.f;
        for (int i = 0; i < 32; ++i) {
            int row = r0 + i * 4 + rowg;
            float4 v = x4[(size_t)row * 1024 + c4];
            sx += v.x; sy += v.y; sz += v.z; sw += v.w;
            ushort4 o; o.x = f2b(v.x); o.y = f2b(v.y); o.z = f2b(v.z); o.w = f2b(v.w);
            *(ushort4*)(xb + (size_t)row * BDIM + c4 * 4) = o;
        }
        red[tid][0] = sx; red[tid][1] = sy; red[tid][2] = sz; red[tid][3] = sw;
        __syncthreads();
        if (tid < 64) {
            for (int j = 64; j < 256; j += 64) {
                sx += red[tid + j][0]; sy += red[tid + j][1];
                sz += red[tid + j][2]; sw += red[tid + j][3];
            }
            int c = bx * 64 + tid;
            atomicAdd(&colsum[c * 4 + 0], sx);
            atomicAdd(&colsum[c * 4 + 1], sy);
            atomicAdd(&colsum[c * 4 + 2], sz);
            atomicAdd(&colsum[c * 4 + 3], sw);
        }
    } else {
        const int wid = bid - 1024;                 // 0..8191
        const float4* src; ushort4* dst; int base;
        if (wid < 4096) { src = wg; dst = wgo; base = wid * 1024 + tid * 4; }
        else            { src = wt; dst = wto; base = (wid - 4096) * 1024 + tid * 4; }
#pragma unroll
        for (int k = 0; k < 4; ++k) {
            float4 v = src[base + k];
            ushort4 o; o.x = f2b(v.x); o.y = f2b(v.y); o.z = f2b(v.z); o.w = f2b(v.w);
            dst[base + k] = o;
        }
    }
}

// ==== ew[row] = cw*(1+tanh(Wamp@mean+bamp));  block 4096 computes sc[] ====
__global__ void k_ew(const float* __restrict__ Wamp, const float* __restrict__ colsum,
                     const float* __restrict__ bamp, const float* __restrict__ cw,
                     const float* __restrict__ Wf, const float* __restrict__ bfp,
                     const float* __restrict__ pmem, const float* __restrict__ cmom,
                     const int* __restrict__ tstep,
                     float* __restrict__ ew, float* __restrict__ sc) {
    __shared__ float red[256];
    const int tid = threadIdx.x;
    if (blockIdx.x < 4096) {
        const int row = blockIdx.x;
        const float4* w4 = (const float4*)(Wamp + (size_t)row * BDIM);
        const float4* m4 = (const float4*)colsum;
        float s = 0.f;
        for (int i = tid; i < 1024; i += 256) {
            float4 w = w4[i], m = m4[i];
            s += w.x * m.x + w.y * m.y + w.z * m.z + w.w * m.w;
        }
        red[tid] = s; __syncthreads();
        for (int off = 128; off > 0; off >>= 1) {
            if (tid < off) red[tid] += red[tid + off];
            __syncthreads();
        }
        if (tid == 0) {
            float v = red[0] * (1.f / (float)BROWS) + bamp[row];
            ew[row] = cw[row] * (1.f + tanhf(v));
        }
    } else {
        float s = 0.f;
        for (int i = tid; i < BDIM; i += 256) s += Wf[i] * colsum[i];
        red[tid] = s; __syncthreads();
        for (int off = 128; off > 0; off >>= 1) {
            if (tid < off) red[tid] += red[tid + off];
            __syncthreads();
        }
        if (tid == 0) {
            const float TP = 6.283185307179586f;
            float mdot = red[0] * (1.f / (float)BROWS) + bfp[0];
            float fa = 1.f / (1.f + expf(-mdot));
            int ts = tstep[0] + 1;
            float t = (float)ts / 100.f;
            float af = 1.618033f * (1.f + fa * 0.2f);
            float pp = fmodf(TP * t * af, TP);
            float sp = fmodf(pp / 1.618033f, TP);
            float co = 0.3f * (sinf(pp) + 0.3f * cosf(sp));
            float d[25];
            d[0] = pp - pmem[0];
            for (int j = 1; j < 25; ++j) d[j] = pmem[2 * j - 1] - pmem[2 * j];
            float m = 0.f;
            for (int j = 0; j < 25; ++j) m += d[j];
            m *= (1.f / 25.f);
            float var = 0.f;
            for (int j = 0; j < 25; ++j) { float e = d[j] - m; var += e * e; }
            var *= (1.f / 24.f);
            float sd = sqrtf(var);
            float pc = fminf(fmaxf(1.f - sd / TP, 0.f), 1.f);
            float cc = 0.9f * (1.f + pc * 0.2f);
            float stab = fminf((float)ts / 1000.f, 1.f);
            float coh1 = cc * (1.f + stab * 0.3f);
            float nm = 0.98f * cmom[0] + 0.02f * coh1;
            float coh = fminf(fmaxf(nm, 0.72f), 1.35f);
            float tf = 1.f + fminf((float)ts / 5000.f, 0.5f);
            sc[0] = co;
            sc[1] = coh * 1.2f * tf * 0.3f;
            sc[2] = (1.f + coh * 0.2f * tf) * 0.15f;
        }
    }
}

// ================= 256x256 pipelined bf16 NT GEMM (lead-1, safe) =========
// 8 waves (2Mx4N), per-wave C 128x64, BK=64, XOR-chunk LDS swizzle (0-conflict).
// Double buffer; during tile T stage tile T+1 into the OPPOSITE buffer N.
// 4 phases, ONE barrier/phase. Issue: P1 b01(T+1); P2 a01,b23(T+1); P3 a23(T+1).
// Reads: P1-top a-lo(T)+q1(T); P2-end a-hi(T); P4-top q0(T+1) from N.
// Waits (per-wave FIFO-traced; steady outstanding = 2 entering P1, max 8):
//   W1=vmcnt(2) drains a23(T)          -> P2's a-hi read safe (wait<barrier<read)
//   W3=vmcnt(6) drains b01(T+1)        -> P4's q0 read safe
//   W4=vmcnt(2) drains a01,b23(T+1)    -> P1(T+1) a-lo/q1 reads safe
// WAR: all stages target buffer N whose regions were last read >=5 phases
// earlier (tile T-1 reads) -> no live-buffer overwrite (round-2 bug fixed).
template <bool STAGE, int W1, int W3, int W4, bool LAST>
__device__ __forceinline__ void tile4(
    const u16* Ab, const u16* Bb, u16* An, u16* Bn, int ks,
    const u16* Ag, const u16* Bg, int loff,
    const int (&rowA)[4], const int (&rowB)[4],
    const int (&aLd)[4], const int (&bLd)[4],
    int apos, int bpos, int c0, int c1,
    bf16x8 (&a)[4][2], bf16x8 (&q0)[2][2], bf16x8 (&q1)[2][2],
    f32x4 (&acc)[8][4])
{
    // ---------------- P1: Q00 = a-lo x q0 ----------------
#pragma unroll
    for (int f = 0; f < 4; ++f) {
        a[f][0] = *(const bf16x8*)(Ab + apos + f * 1024 + c0);
        a[f][1] = *(const bf16x8*)(Ab + apos + f * 1024 + c1);
    }
#pragma unroll
    for (int f = 0; f < 2; ++f) {
        q1[f][0] = *(const bf16x8*)(Bb + bpos + (2 + f) * 1024 + c0);
        q1[f][1] = *(const bf16x8*)(Bb + bpos + (2 + f) * 1024 + c1);
    }
    if constexpr (STAGE) {
        gload16(Bg + (size_t)rowB[0] * GK + loff + ks, Bn + bLd[0]);
        gload16(Bg + (size_t)rowB[1] * GK + loff + ks, Bn + bLd[1]);
    }
    __builtin_amdgcn_s_setprio(1);
#pragma unroll
    for (int mf = 0; mf < 4; ++mf)
#pragma unroll
        for (int nf = 0; nf < 2; ++nf) {
            acc[mf][nf] = __builtin_amdgcn_mfma_f32_16x16x32_bf16(a[mf][0], q0[nf][0], acc[mf][nf], 0, 0, 0);
            acc[mf][nf] = __builtin_amdgcn_mfma_f32_16x16x32_bf16(a[mf][1], q0[nf][1], acc[mf][nf], 0, 0, 0);
        }
    __builtin_amdgcn_s_setprio(0);
    vwait<W1>();
    __builtin_amdgcn_s_barrier();
    __builtin_amdgcn_sched_barrier(0);

    // ---------------- P2: Q01 = a-lo x q1; then read a-hi ----------------
    if constexpr (STAGE) {
        gload16(Ag + (size_t)rowA[0] * GK + loff + ks, An + aLd[0]);
        gload16(Ag + (size_t)rowA[1] * GK + loff + ks, An + aLd[1]);
        gload16(Bg + (size_t)rowB[2] * GK + loff + ks, Bn + bLd[2]);
        gload16(Bg + (size_t)rowB[3] * GK + loff + ks, Bn + bLd[3]);
    }
    __builtin_amdgcn_s_setprio(1);
#pragma unroll
    for (int mf = 0; mf < 4; ++mf)
#pragma unroll
        for (int nf = 0; nf < 2; ++nf) {
            acc[mf][2 + nf] = __builtin_amdgcn_mfma_f32_16x16x32_bf16(a[mf][0], q1[nf][0], acc[mf][2 + nf], 0, 0, 0);
            acc[mf][2 + nf] = __builtin_amdgcn_mfma_f32_16x16x32_bf16(a[mf][1], q1[nf][1], acc[mf][2 + nf], 0, 0, 0);
        }
    __builtin_amdgcn_s_setprio(0);
#pragma unroll
    for (int f = 0; f < 4; ++f) {        // a-hi (WAR-ordered after Q01)
        a[f][0] = *(const bf16x8*)(Ab + apos + (4 + f) * 1024 + c0);
        a[f][1] = *(const bf16x8*)(Ab + apos + (4 + f) * 1024 + c1);
    }
    __builtin_amdgcn_s_barrier();
    __builtin_amdgcn_sched_barrier(0);

    // ---------------- P3: Q10 = a-hi x q0 ----------------
    if constexpr (STAGE) {
        gload16(Ag + (size_t)rowA[2] * GK + loff + ks, An + aLd[2]);
        gload16(Ag + (size_t)rowA[3] * GK + loff + ks, An + aLd[3]);
    }
    __builtin_amdgcn_s_setprio(1);
#pragma unroll
    for (int mf = 0; mf < 4; ++mf)
#pragma unroll
        for (int nf = 0; nf < 2; ++nf) {
            acc[4 + mf][nf] = __builtin_amdgcn_mfma_f32_16x16x32_bf16(a[mf][0], q0[nf][0], acc[4 + mf][nf], 0, 0, 0);
            acc[4 + mf][nf] = __builtin_amdgcn_mfma_f32_16x16x32_bf16(a[mf][1], q0[nf][1], acc[4 + mf][nf], 0, 0, 0);
        }
    __builtin_amdgcn_s_setprio(0);
    vwait<W3>();
    __builtin_amdgcn_s_barrier();
    __builtin_amdgcn_sched_barrier(0);

    // ---------------- P4: Q11 = a-hi x q1; prefetch q0(T+1) from N -------
    if constexpr (!LAST) {
#pragma unroll
        for (int f = 0; f < 2; ++f) {
            q0[f][0] = *(const bf16x8*)(Bn + bpos + f * 1024 + c0);
            q0[f][1] = *(const bf16x8*)(Bn + bpos + f * 1024 + c1);
        }
    }
    __builtin_amdgcn_s_setprio(1);
#pragma unroll
    for (int mf = 0; mf < 4; ++mf)
#pragma unroll
        for (int nf = 0; nf < 2; ++nf) {
            acc[4 + mf][2 + nf] = __builtin_amdgcn_mfma_f32_16x16x32_bf16(a[mf][0], q1[nf][0], acc[4 + mf][2 + nf], 0, 0, 0);
            acc[4 + mf][2 + nf] = __builtin_amdgcn_mfma_f32_16x16x32_bf16(a[mf][1], q1[nf][1], acc[4 + mf][2 + nf], 0, 0, 0);
        }
    __builtin_amdgcn_s_setprio(0);
    vwait<W4>();
    __builtin_amdgcn_s_barrier();
    __builtin_amdgcn_sched_barrier(0);
}

// MODE 1: enh_bf = bf16( xf + csef(col) * sigmoid(acc + bias[col]) ),
//         csef(col) = (0.98*cstate + 0.02*sc0*ew)*sc1 computed inline
// MODE 2: outf = b2f(A[row,col]) + tanh(acc + bias[col]) * sc[2]
template <int MODE>
__global__ __launch_bounds__(512, 2) void gemm256(
    const u16* __restrict__ A, const u16* __restrict__ Bm,
    const float* __restrict__ xf, const float* __restrict__ bias,
    const float* __restrict__ cstate, const float* __restrict__ ew,
    const float* __restrict__ sc,
    u16* __restrict__ outb, float* __restrict__ outf)
{
    __shared__ u16 As[2 * BUF];
    __shared__ u16 Bs[2 * BUF];

    const int tid  = threadIdx.x;
    const int lane = tid & 63;
    const int wave = tid >> 6;
    const int wm = wave >> 2;
    const int wn = wave & 3;

    const int bid = blockIdx.x;
    const int swz = (bid & 7) * 64 + (bid >> 3);
    const int bn0 = (swz >> 5) * 256;
    const int bm0 = (swz & 31) * 256;

    const int lr = lane >> 3, lc = lane & 7;
    const int loff = lr * GK + (lc ^ lr) * 8;      // per-lane global offset (pre-swizzled)
    const int rA = wn;
    const int rB = wm * 2 + (wn & 1);
    int rowA[4], rowB[4], aLd[4], bLd[4];
    {
        const int aw[4] = {rA, 4 + rA, 8 + rA, 12 + rA};       // 0,1=lo  2,3=hi
        const int bw[4] = {rB, 8 + rB, 4 + rB, 12 + rB};       // 0,1=lo  2,3=hi
#pragma unroll
        for (int j = 0; j < 4; ++j) {
            rowA[j] = rfl(bm0 + wm * 128 + aw[j] * 8);
            rowB[j] = rfl(bn0 + (wn >> 1) * 128 + bw[j] * 8);
            aLd[j]  = rfl((wm * 128 + aw[j] * 8) * 64);
            bLd[j]  = rfl(((wn >> 1) * 128 + bw[j] * 8) * 64);
        }
    }

    const int lm   = lane & 15;
    const int quad = lane >> 4;
    const int rsw  = lm & 7;
    const int apos = (wm * 128 + lm) * 64;
    const int bpos = (wn * 64 + lm) * 64;
    const int c0 = (quad ^ rsw) * 8;
    const int c1 = ((4 + quad) ^ rsw) * 8;

    f32x4 acc[8][4];
#pragma unroll
    for (int i = 0; i < 8; ++i)
#pragma unroll
        for (int j = 0; j < 4; ++j) acc[i][j] = (f32x4){0.f, 0.f, 0.f, 0.f};

    // ---- prologue: stage tile 0 into buf0, FIFO order [B01, A01, B23, A23] ----
    gload16(Bm + (size_t)rowB[0] * GK + loff, Bs + bLd[0]);
    gload16(Bm + (size_t)rowB[1] * GK + loff, Bs + bLd[1]);
    gload16(A  + (size_t)rowA[0] * GK + loff, As + aLd[0]);
    gload16(A  + (size_t)rowA[1] * GK + loff, As + aLd[1]);
    gload16(Bm + (size_t)rowB[2] * GK + loff, Bs + bLd[2]);
    gload16(Bm + (size_t)rowB[3] * GK + loff, Bs + bLd[3]);
    gload16(A  + (size_t)rowA[2] * GK + loff, As + aLd[2]);
    gload16(A  + (size_t)rowA[3] * GK + loff, As + aLd[3]);
    vwait<2>();                        // drain B01,A01,B23 of tile 0 (a23 outstanding)
    __builtin_amdgcn_s_barrier();
    __builtin_amdgcn_sched_barrier(0);

    bf16x8 a[4][2], q0[2][2], q1[2][2];
#pragma unroll
    for (int f = 0; f < 2; ++f) {      // pre-read q0(0) from buf0
        q0[f][0] = *(const bf16x8*)(Bs + bpos + f * 1024 + c0);
        q0[f][1] = *(const bf16x8*)(Bs + bpos + f * 1024 + c1);
    }

    // tiles 0..61 (paired for static buffer parity), each stages T+1
    for (int T = 0; T < 62; T += 2) {
        tile4<true, 2, 6, 2, false>(
            As, Bs, As + BUF, Bs + BUF, (T + 1) * 64,
            A, Bm, loff, rowA, rowB, aLd, bLd,
            apos, bpos, c0, c1, a, q0, q1, acc);
        tile4<true, 2, 6, 2, false>(
            As + BUF, Bs + BUF, As, Bs, (T + 2) * 64,
            A, Bm, loff, rowA, rowB, aLd, bLd,
            apos, bpos, c0, c1, a, q0, q1, acc);
    }
    // tile 62: read buf0, stage tile 63 into buf1
    tile4<true, 2, 6, 2, false>(
        As, Bs, As + BUF, Bs + BUF, 63 * 64,
        A, Bm, loff, rowA, rowB, aLd, bLd,
        apos, bpos, c0, c1, a, q0, q1, acc);
    // tile 63 (LAST): read buf1, no staging; W1=vmcnt(0) before a-hi read
    tile4<false, 0, -1, -1, true>(
        As + BUF, Bs + BUF, As, Bs, 0,
        A, Bm, loff, rowA, rowB, aLd, bLd,
        apos, bpos, c0, c1, a, q0, q1, acc);

    // ---- epilogue ----
    const int col0 = bn0 + wn * 64 + lm;
    const int row0 = bm0 + wm * 128 + quad * 4;
    float bias_v[4], csef_v[4];
    float sc0 = 0.f, sc1 = 0.f, tb15 = 0.f;
    if (MODE == 1) { sc0 = sc[0]; sc1 = sc[1]; }
    else           { tb15 = sc[2]; }
#pragma unroll
    for (int nf = 0; nf < 4; ++nf) {
        const int col = col0 + nf * 16;
        bias_v[nf] = bias[col];
        if (MODE == 1)
            csef_v[nf] = (0.98f * cstate[col] + 0.02f * sc0 * ew[col]) * sc1;
    }
#pragma unroll
    for (int mf = 0; mf < 8; ++mf) {
#pragma unroll
        for (int r = 0; r < 4; ++r) {
            const int row = row0 + mf * 16 + r;
#pragma unroll
            for (int nf = 0; nf < 4; ++nf) {
                const int col = col0 + nf * 16;
                const float v = acc[mf][nf][r];
                const size_t idx = (size_t)row * GN + col;
                if (MODE == 1) {
                    float vb = v + bias_v[nf];
                    vb = fminf(fmaxf(vb, -30.f), 30.f);
                    float sg = 1.f / (1.f + __expf(-vb));
                    float e = xf[idx] + csef_v[nf] * sg;
                    outb[idx] = f2b(e);
                } else {
                    float vb = v + bias_v[nf];
                    vb = fminf(fmaxf(vb, -15.f), 15.f);
                    float e2 = __expf(2.f * vb);
                    float th = (e2 - 1.f) / (e2 + 1.f);
                    outf[idx] = b2f(A[idx]) + th * tb15;
                }
            }
        }
    }
}

extern "C" void kernel_launch(void* const* d_in, const int* in_sizes, int n_in,
                              void* d_out, int out_size, void* d_ws, size_t ws_size,
                              hipStream_t stream) {
    const float* x      = (const float*)d_in[0];
    const float* cstate = (const float*)d_in[1];
    const float* pmem   = (const float*)d_in[2];
    const float* cmom   = (const float*)d_in[3];
    const float* cw     = (const float*)d_in[4];
    const float* Wf     = (const float*)d_in[5];
    const float* bfp    = (const float*)d_in[6];
    const float* Wamp   = (const float*)d_in[7];
    const float* bamp   = (const float*)d_in[8];
    const float* Wtemp  = (const float*)d_in[9];
    const float* btemp  = (const float*)d_in[10];
    const float* Wgate  = (const float*)d_in[11];
    const float* bgate  = (const float*)d_in[12];
    const int*   tstep  = (const int*)d_in[13];
    float* out = (float*)d_out;

    char* ws = (char*)d_ws;
    u16* x_bf   = (u16*)ws;  ws += (size_t)BROWS * BDIM * 2;   // 64 MB
    u16* wg_bf  = (u16*)ws;  ws += (size_t)BDIM * BDIM * 2;    // 32 MB
    u16* wt_bf  = (u16*)ws;  ws += (size_t)BDIM * BDIM * 2;    // 32 MB
    u16* enh_bf = (u16*)ws;  ws += (size_t)BROWS * BDIM * 2;   // 64 MB
    float* colsum = (float*)ws; ws += BDIM * 4;
    float* ew     = (float*)ws; ws += BDIM * 4;
    float* sc     = (float*)ws; ws += 256;

    hipMemsetAsync(colsum, 0, BDIM * sizeof(float), stream);
    k_prep<<<9216, 256, 0, stream>>>(x, x_bf, colsum,
                                     (const float4*)Wgate, (ushort4*)wg_bf,
                                     (const float4*)Wtemp, (ushort4*)wt_bf);
    k_ew<<<4097, 256, 0, stream>>>(Wamp, colsum, bamp, cw, Wf, bfp, pmem, cmom,
                                   tstep, ew, sc);
    gemm256<1><<<512, 512, 0, stream>>>(x_bf, wg_bf, x, bgate, cstate, ew, sc, enh_bf, nullptr);
    gemm256<2><<<512, 512, 0, stream>>>(enh_bf, wt_bf, nullptr, btemp, nullptr, nullptr, sc, nullptr, out);
}